// Round 7
// baseline (341.781 us; speedup 1.0000x reference)
//
#include <hip/hip_runtime.h>
#include <stdint.h>

#define CCC_EPS 1e-8
#define SEGS 4           // blocks per row
#define TPB 256
#define PER_THREAD 16    // vec4 per array per thread (SEGS*TPB*PER_THREAD*4 == T)
#define DEPTH 8          // LDS ring slots per wave per array
#define AHEAD 6          // DMA issue distance (slots ahead of consumption)

typedef float floatx4 __attribute__((ext_vector_type(4)));

// Round-7: (a) revert R6's split-residency (null on duration: FETCH halved to
// 134 MB yet dur unchanged 79 us -> the ~3.5 TB/s read ceiling is common to
// L3 and HBM; temporal alloc only perturbed fills. Both arrays NT again).
// (b) Fuse the final reduction into the partial kernel via last-block ticket:
// removes the second launch + gap (~11 us of the 246 total), the only
// controllable term left — the partial kernel itself runs AT the measured
// chip read roofline (268 MB / 3.5 TB/s = 76 us vs 75-79 measured; invariant
// across occupancy, pipeline depth, return path, and data source R1-R6).
//
// Last-block pattern: stores -> __threadfence (release, wbl2) -> device-scope
// atomicAdd ticket. Tickets are a contiguous run of 2048 values, so
// (ticket & 2047) == 2047 selects exactly one block for ANY starting counter
// value -> no memset, immune to workspace poisoning, uint32 wrap harmless.
// The last block re-runs the OLD final kernel's math bit-identically:
// thread t handles rows t and t+256 separately (v0/v1), wave-reduces each
// with the same shfl tree (= old waves w and w+4), fred[0..7] summed in the
// same order by thread 0 -> identical FP tree -> absmax stays 0.0.
template <int N>
__device__ __forceinline__ void wait_vmcnt() {
    asm volatile("s_waitcnt vmcnt(%0)" :: "n"(N) : "memory");
}

__device__ __forceinline__ void gld_lds16(const void* g, void* l) {
    __builtin_amdgcn_global_load_lds(
        (const __attribute__((address_space(1))) uint32_t*)(uintptr_t)g,
        (__attribute__((address_space(3))) uint32_t*)(uint32_t)(uintptr_t)l,
        16, 0, 2 /* CPol: NT */);
}

// Exact copy of the old final kernel's per-row math (double combine).
__device__ __forceinline__ float loss_row(const float* __restrict__ partial,
                                          int b, int T) {
    double tsx = 0, tsy = 0, tsxx = 0, tsyy = 0, tsxy = 0;
    const float* src = partial + (size_t)b * SEGS * 5;
    #pragma unroll
    for (int s = 0; s < SEGS; ++s) {
        tsx  += src[s * 5 + 0];
        tsy  += src[s * 5 + 1];
        tsxx += src[s * 5 + 2];
        tsyy += src[s * 5 + 3];
        tsxy += src[s * 5 + 4];
    }
    const double inv = 1.0 / (double)T;
    const double mx = tsx * inv;
    const double my = tsy * inv;
    const double vx = tsxx * inv - mx * mx;
    const double vy = tsyy * inv - my * my;
    const double cov = tsxy * inv - mx * my;
    const double d = mx - my;
    const double ccc = 2.0 * cov / (vx + vy + d * d + CCC_EPS);
    return (float)(1.0 - ccc);
}

__global__ __launch_bounds__(TPB, 4) void ccc_fused_kernel(
    const float* __restrict__ preds,
    const float* __restrict__ labels,
    float* __restrict__ partial,        // [B*SEGS*5]
    unsigned int* __restrict__ counter, // 1 uint (never reset; see header)
    float* __restrict__ out,
    int T, int B)
{
    const int seg = blockIdx.x & (SEGS - 1);
    const int row = blockIdx.x >> 2;                 // SEGS == 4
    const int seg4 = (T >> 2) / SEGS;                // 4096 vec4
    const size_t base4 = (size_t)row * (size_t)(T >> 2) + (size_t)seg * seg4;
    const floatx4* __restrict__ p4 = (const floatx4*)preds + base4;
    const floatx4* __restrict__ l4 = (const floatx4*)labels + base4;

    // Per-wave private staging rings: [wave][slot][lane] of 16B. 64 KB total
    // -> 2 blocks/CU (128 of 160 KB LDS).
    __shared__ floatx4 lx[4][DEPTH][64];
    __shared__ floatx4 ly[4][DEPTH][64];

    const int wave = threadIdx.x >> 6;
    const int lane = threadIdx.x & 63;

    float sx = 0.f, sy = 0.f, sxx = 0.f, syy = 0.f, sxy = 0.f;

    // DMA slot s: lane L of wave w sources p4/l4[s*TPB + w*64 + L] (== the
    // element thread (w,L) consumed in the original kernel at k=s) and lands
    // at ring[w][s&7] + L*16 (HW appends lane*size to the wave-uniform base).
#define ISSUE(s)                                                              \
    do {                                                                      \
        if ((s) < PER_THREAD) {                                               \
            const int _sl = (s) & (DEPTH - 1);                                \
            gld_lds16(&p4[(size_t)(s) * TPB + threadIdx.x], &lx[wave][_sl][0]); \
            gld_lds16(&l4[(size_t)(s) * TPB + threadIdx.x], &ly[wave][_sl][0]); \
        }                                                                     \
    } while (0)

#define CONSUME(k)                                                            \
    do {                                                                      \
        const int _sl = (k) & (DEPTH - 1);                                    \
        floatx4 x = lx[wave][_sl][lane];                                      \
        floatx4 y = ly[wave][_sl][lane];                                      \
        sx  += x.x + x.y + x.z + x.w;                                         \
        sy  += y.x + y.y + y.z + y.w;                                         \
        sxx = fmaf(x.x, x.x, sxx); sxx = fmaf(x.y, x.y, sxx);                 \
        sxx = fmaf(x.z, x.z, sxx); sxx = fmaf(x.w, x.w, sxx);                 \
        syy = fmaf(y.x, y.x, syy); syy = fmaf(y.y, y.y, syy);                 \
        syy = fmaf(y.z, y.z, syy); syy = fmaf(y.w, y.w, syy);                 \
        sxy = fmaf(x.x, y.x, sxy); sxy = fmaf(x.y, y.y, sxy);                 \
        sxy = fmaf(x.z, y.z, sxy); sxy = fmaf(x.w, y.w, sxy);                 \
    } while (0)

    // vmcnt accounting: entering STEP(k), pairs for slots k..k+AHEAD-1 are
    // outstanding (12 ops). ISSUE(k+AHEAD) makes it 14; vmcnt(12) retires the
    // oldest pair (slot k). Tail: no issue, outstanding = 2*(16-k), wait
    // 2*(15-k). Only VMEM ops in the loop are these DMAs, so counts are exact.
#define VMN(k) (((k) + AHEAD < PER_THREAD) ? (2 * AHEAD) : (2 * (PER_THREAD - 1 - (k))))
#define STEP(k)                                                               \
    do {                                                                      \
        ISSUE((k) + AHEAD);                                                   \
        wait_vmcnt<VMN(k)>();                                                 \
        CONSUME(k);                                                           \
    } while (0)

    ISSUE(0); ISSUE(1); ISSUE(2); ISSUE(3); ISSUE(4); ISSUE(5);
    STEP(0);  STEP(1);  STEP(2);  STEP(3);
    STEP(4);  STEP(5);  STEP(6);  STEP(7);
    STEP(8);  STEP(9);  STEP(10); STEP(11);
    STEP(12); STEP(13); STEP(14); STEP(15);

#undef STEP
#undef VMN
#undef CONSUME
#undef ISSUE

    // 64-lane wave reduction
    #pragma unroll
    for (int off = 32; off > 0; off >>= 1) {
        sx  += __shfl_down(sx,  off);
        sy  += __shfl_down(sy,  off);
        sxx += __shfl_down(sxx, off);
        syy += __shfl_down(syy, off);
        sxy += __shfl_down(sxy, off);
    }

    __shared__ float red[4][5];
    if (lane == 0) {
        red[wave][0] = sx;  red[wave][1] = sy;  red[wave][2] = sxx;
        red[wave][3] = syy; red[wave][4] = sxy;
    }
    __syncthreads();

    __shared__ int is_last;
    if (threadIdx.x == 0) {
        float t0 = red[0][0] + red[1][0] + red[2][0] + red[3][0];
        float t1 = red[0][1] + red[1][1] + red[2][1] + red[3][1];
        float t2 = red[0][2] + red[1][2] + red[2][2] + red[3][2];
        float t3 = red[0][3] + red[1][3] + red[2][3] + red[3][3];
        float t4 = red[0][4] + red[1][4] + red[2][4] + red[3][4];
        float* dst = partial + ((size_t)row * SEGS + seg) * 5;
        dst[0] = t0; dst[1] = t1; dst[2] = t2; dst[3] = t3; dst[4] = t4;

        __threadfence();  // release: make stores visible device-wide (wbl2)
        const unsigned int nblk = (unsigned int)(B * SEGS);    // 2048, pow2
        unsigned int ticket = atomicAdd(counter, 1u);
        is_last = ((ticket & (nblk - 1u)) == (nblk - 1u));
    }
    __syncthreads();
    if (!is_last) return;

    __threadfence();  // acquire: invalidate stale cached lines before reads

    // ---- Fused finalization: bit-identical to the old 512-thread final
    // kernel. Thread t = old threads t and t+256; same per-row double math;
    // same 64-lane shfl tree (our wave w reproduces old waves w and w+4);
    // fred[0..7] summed in the old order by thread 0.
    float v0 = loss_row(partial, threadIdx.x, T);          // rows 0..255
    float v1 = loss_row(partial, threadIdx.x + TPB, T);    // rows 256..511

    #pragma unroll
    for (int off = 32; off > 0; off >>= 1) {
        v0 += __shfl_down(v0, off);
        v1 += __shfl_down(v1, off);
    }

    __shared__ float fred[8];
    if (lane == 0) { fred[wave] = v0; fred[wave + 4] = v1; }
    __syncthreads();
    if (threadIdx.x == 0) {
        float t = 0.f;
        #pragma unroll
        for (int w = 0; w < 8; ++w) t += fred[w];
        out[0] = t / (float)B;
    }
}

extern "C" void kernel_launch(void* const* d_in, const int* in_sizes, int n_in,
                              void* d_out, int out_size, void* d_ws, size_t ws_size,
                              hipStream_t stream) {
    const float* preds  = (const float*)d_in[0];
    const float* labels = (const float*)d_in[1];
    float* out = (float*)d_out;

    const int T = 65536;
    const int B = in_sizes[0] / T;   // 512

    float* partial = (float*)d_ws;                       // B*SEGS*5 floats
    unsigned int* counter = (unsigned int*)((char*)d_ws + (size_t)B * SEGS * 5 * sizeof(float));

    ccc_fused_kernel<<<B * SEGS, TPB, 0, stream>>>(preds, labels, partial,
                                                   counter, out, T, B);
}

// Round 8
// 247.776 us; speedup vs baseline: 1.3794x; 1.3794x over previous
//
#include <hip/hip_runtime.h>
#include <stdint.h>

#define CCC_EPS 1e-8
#define SEGS 4           // blocks per row
#define TPB 256
#define PER_THREAD 16    // vec4 per array per thread (SEGS*TPB*PER_THREAD*4 == T)
#define DEPTH 8          // LDS ring slots per wave per array
#define AHEAD 6          // DMA issue distance (slots ahead of consumption)

typedef float floatx4 __attribute__((ext_vector_type(4)));

// Round-8: revert to the R5 kernel (session best, 246.1 us). R7's last-block
// fusion regressed 95 us: per-block __threadfence() across non-coherent
// per-XCD L2s costs far more than the ~11 us second launch it saved — the
// kernel boundary IS the cheap cross-XCD flush.
//
// Session conclusion encoded here: delivered-read BW caps at ~3.4-3.6 TB/s
// invariant to occupancy (R1), cache policy (R3), per-wave VGPR pipeline
// depth (R4), LDS-DMA return path (R5), and data source HBM vs L3 (R6/R7
// FETCH halving with dur unchanged). 268 MB / 3.5 TB/s = 76 us = measured
// partial duration -> the read phase is AT the chip's delivered-read
// ceiling (consistent with m13: 6.29 TB/s copy = ~3.15 read + ~3.15 write).
template <int N>
__device__ __forceinline__ void wait_vmcnt() {
    asm volatile("s_waitcnt vmcnt(%0)" :: "n"(N) : "memory");
}

__device__ __forceinline__ void gld_lds16(const void* g, void* l) {
    __builtin_amdgcn_global_load_lds(
        (const __attribute__((address_space(1))) uint32_t*)(uintptr_t)g,
        (__attribute__((address_space(3))) uint32_t*)(uint32_t)(uintptr_t)l,
        16, 0, 2 /* CPol: NT */);
}

__global__ __launch_bounds__(TPB, 4) void ccc_partial_kernel(
    const float* __restrict__ preds,
    const float* __restrict__ labels,
    float* __restrict__ partial,   // [B*SEGS*5]
    int T)
{
    const int seg = blockIdx.x & (SEGS - 1);
    const int row = blockIdx.x >> 2;                 // SEGS == 4
    const int seg4 = (T >> 2) / SEGS;                // 4096 vec4
    const size_t base4 = (size_t)row * (size_t)(T >> 2) + (size_t)seg * seg4;
    const floatx4* __restrict__ p4 = (const floatx4*)preds + base4;
    const floatx4* __restrict__ l4 = (const floatx4*)labels + base4;

    // Per-wave private staging rings: [wave][slot][lane] of 16B. 64 KB total
    // -> 2 blocks/CU (128 of 160 KB LDS).
    __shared__ floatx4 lx[4][DEPTH][64];
    __shared__ floatx4 ly[4][DEPTH][64];

    const int wave = threadIdx.x >> 6;
    const int lane = threadIdx.x & 63;

    float sx = 0.f, sy = 0.f, sxx = 0.f, syy = 0.f, sxy = 0.f;

    // DMA slot s: lane L of wave w sources p4/l4[s*TPB + w*64 + L] (== the
    // element thread (w,L) consumed in the original kernel at k=s) and lands
    // at ring[w][s&7] + L*16 (HW appends lane*size to the wave-uniform base).
#define ISSUE(s)                                                              \
    do {                                                                      \
        if ((s) < PER_THREAD) {                                               \
            const int _sl = (s) & (DEPTH - 1);                                \
            gld_lds16(&p4[(size_t)(s) * TPB + threadIdx.x], &lx[wave][_sl][0]); \
            gld_lds16(&l4[(size_t)(s) * TPB + threadIdx.x], &ly[wave][_sl][0]); \
        }                                                                     \
    } while (0)

#define CONSUME(k)                                                            \
    do {                                                                      \
        const int _sl = (k) & (DEPTH - 1);                                    \
        floatx4 x = lx[wave][_sl][lane];                                      \
        floatx4 y = ly[wave][_sl][lane];                                      \
        sx  += x.x + x.y + x.z + x.w;                                         \
        sy  += y.x + y.y + y.z + y.w;                                         \
        sxx = fmaf(x.x, x.x, sxx); sxx = fmaf(x.y, x.y, sxx);                 \
        sxx = fmaf(x.z, x.z, sxx); sxx = fmaf(x.w, x.w, sxx);                 \
        syy = fmaf(y.x, y.x, syy); syy = fmaf(y.y, y.y, syy);                 \
        syy = fmaf(y.z, y.z, syy); syy = fmaf(y.w, y.w, syy);                 \
        sxy = fmaf(x.x, y.x, sxy); sxy = fmaf(x.y, y.y, sxy);                 \
        sxy = fmaf(x.z, y.z, sxy); sxy = fmaf(x.w, y.w, sxy);                 \
    } while (0)

    // vmcnt accounting: entering STEP(k), pairs for slots k..k+AHEAD-1 are
    // outstanding (12 ops). ISSUE(k+AHEAD) makes it 14; vmcnt(12) retires the
    // oldest pair (slot k). Tail: no issue, outstanding = 2*(16-k), wait
    // 2*(15-k). Only VMEM ops in the loop are these DMAs, so counts are exact.
#define VMN(k) (((k) + AHEAD < PER_THREAD) ? (2 * AHEAD) : (2 * (PER_THREAD - 1 - (k))))
#define STEP(k)                                                               \
    do {                                                                      \
        ISSUE((k) + AHEAD);                                                   \
        wait_vmcnt<VMN(k)>();                                                 \
        CONSUME(k);                                                           \
    } while (0)

    ISSUE(0); ISSUE(1); ISSUE(2); ISSUE(3); ISSUE(4); ISSUE(5);
    STEP(0);  STEP(1);  STEP(2);  STEP(3);
    STEP(4);  STEP(5);  STEP(6);  STEP(7);
    STEP(8);  STEP(9);  STEP(10); STEP(11);
    STEP(12); STEP(13); STEP(14); STEP(15);

#undef STEP
#undef VMN
#undef CONSUME
#undef ISSUE

    // 64-lane wave reduction
    #pragma unroll
    for (int off = 32; off > 0; off >>= 1) {
        sx  += __shfl_down(sx,  off);
        sy  += __shfl_down(sy,  off);
        sxx += __shfl_down(sxx, off);
        syy += __shfl_down(syy, off);
        sxy += __shfl_down(sxy, off);
    }

    __shared__ float red[4][5];
    if (lane == 0) {
        red[wave][0] = sx;  red[wave][1] = sy;  red[wave][2] = sxx;
        red[wave][3] = syy; red[wave][4] = sxy;
    }
    __syncthreads();

    if (threadIdx.x == 0) {
        float t0 = red[0][0] + red[1][0] + red[2][0] + red[3][0];
        float t1 = red[0][1] + red[1][1] + red[2][1] + red[3][1];
        float t2 = red[0][2] + red[1][2] + red[2][2] + red[3][2];
        float t3 = red[0][3] + red[1][3] + red[2][3] + red[3][3];
        float t4 = red[0][4] + red[1][4] + red[2][4] + red[3][4];
        float* dst = partial + ((size_t)row * SEGS + seg) * 5;
        dst[0] = t0; dst[1] = t1; dst[2] = t2; dst[3] = t3; dst[4] = t4;
    }
}

// Single block: one thread per row combines its SEGS partials in double,
// computes (1 - ccc), then block-reduces the mean.
__global__ __launch_bounds__(512) void ccc_final_kernel(
    const float* __restrict__ partial,
    float* __restrict__ out,
    int B, int T)
{
    float loss_sum = 0.f;
    for (int b = threadIdx.x; b < B; b += 512) {
        double tsx = 0, tsy = 0, tsxx = 0, tsyy = 0, tsxy = 0;
        const float* src = partial + (size_t)b * SEGS * 5;
        #pragma unroll
        for (int s = 0; s < SEGS; ++s) {
            tsx  += src[s * 5 + 0];
            tsy  += src[s * 5 + 1];
            tsxx += src[s * 5 + 2];
            tsyy += src[s * 5 + 3];
            tsxy += src[s * 5 + 4];
        }
        const double inv = 1.0 / (double)T;
        const double mx = tsx * inv;
        const double my = tsy * inv;
        const double vx = tsxx * inv - mx * mx;
        const double vy = tsyy * inv - my * my;
        const double cov = tsxy * inv - mx * my;
        const double d = mx - my;
        const double ccc = 2.0 * cov / (vx + vy + d * d + CCC_EPS);
        loss_sum += (float)(1.0 - ccc);
    }

    #pragma unroll
    for (int off = 32; off > 0; off >>= 1) loss_sum += __shfl_down(loss_sum, off);

    __shared__ float red[8];
    const int wave = threadIdx.x >> 6;
    const int lane = threadIdx.x & 63;
    if (lane == 0) red[wave] = loss_sum;
    __syncthreads();
    if (threadIdx.x == 0) {
        float t = 0.f;
        #pragma unroll
        for (int w = 0; w < 8; ++w) t += red[w];
        out[0] = t / (float)B;
    }
}

extern "C" void kernel_launch(void* const* d_in, const int* in_sizes, int n_in,
                              void* d_out, int out_size, void* d_ws, size_t ws_size,
                              hipStream_t stream) {
    const float* preds  = (const float*)d_in[0];
    const float* labels = (const float*)d_in[1];
    float* out = (float*)d_out;

    const int T = 65536;
    const int B = in_sizes[0] / T;   // 512

    float* partial = (float*)d_ws;   // B*SEGS*5 floats

    ccc_partial_kernel<<<B * SEGS, TPB, 0, stream>>>(preds, labels, partial, T);
    ccc_final_kernel<<<1, 512, 0, stream>>>(partial, out, B, T);
}